// Round 19
// baseline (276.153 us; speedup 1.0000x reference)
//
#include <hip/hip_runtime.h>

#define NBATCH 32
#define NFEAT 48
#define C1c 6
#define LRC 42
#define HH 128
#define WW 128
#define HWSZ 16384
#define NP 81
#define NQ 64

// workspace layout (in floats)
#define OFF_PM   0                      // 81*64 = 5184
#define OFF_GAP  5184                   // 32*42 = 1344  (contiguous after PM -> one memset)
#define OFF_K    6528                   // 64*64 = 4096
#define OFF_ATTN 10624                  // 1344
#define OFF_WB   11968                  // 48*48 = 2304 rearranged weights
#define OFF_HR   14272                  // 32*6*16384 = 3145728 (hrbuf; inv reuses it pre-k_hr)
#define OFF_PART (OFF_HR + 4194304)     // 288 * 16384 = 4718592 floats (ws is ~650 MB: safe)

// ---------------- K1a: softmax partial denominators, PLANE-CONTIGUOUS sweeps ----------------
// Block = (image b, p-chunk of 9). Thread owns 16 interleaved float4 accumulators; each of
// the 9 planes is swept with 16 perfectly-coalesced 4KB wave-loads (sm2's proven pattern).
__global__ __launch_bounds__(256) void k_sm1(const float* __restrict__ logits,
                                             float* __restrict__ part) {
    int bid = blockIdx.x;                 // 0..287 = b*9 + chunk
    int b = bid / 9, chunk = bid - b * 9;
    int p0 = chunk * 9;
    int tid = threadIdx.x;
    const float4* lg4 = (const float4*)logits;
    float4 acc[16];
#pragma unroll
    for (int k = 0; k < 16; ++k) acc[k] = make_float4(0.f, 0.f, 0.f, 0.f);
    for (int i = 0; i < 9; ++i) {
        const float4* pl = lg4 + ((size_t)(b * NP + p0 + i) << 12);   // 4096 f4/plane
#pragma unroll
        for (int k = 0; k < 16; ++k) {
            float4 v = pl[(k << 8) + tid];
            acc[k].x += __expf(v.x); acc[k].y += __expf(v.y);
            acc[k].z += __expf(v.z); acc[k].w += __expf(v.w);
        }
    }
    float4* pp = (float4*)part + ((size_t)bid << 12);
#pragma unroll
    for (int k = 0; k < 16; ++k) pp[(k << 8) + tid] = acc[k];
}

// ---------------- K1a': merge 9 partials per image -> inv (at OFF_HR) ----------------
__global__ __launch_bounds__(256) void k_minv(const float* __restrict__ part,
                                              float* __restrict__ invbuf) {
    int idx = blockIdx.x * 256 + threadIdx.x;     // 0..131071 (float4 index)
    int b = idx >> 12, i = idx & 4095;
    const float4* p4 = (const float4*)part;
    float sx = 0.f, sy = 0.f, sz = 0.f, sw = 0.f;
#pragma unroll
    for (int c = 0; c < 9; ++c) {
        float4 v = p4[((size_t)(b * 9 + c) << 12) + i];
        sx += v.x; sy += v.y; sz += v.z; sw += v.w;
    }
    ((float4*)invbuf)[idx] = make_float4(1.f / sx, 1.f / sy, 1.f / sz, 1.f / sw);
}

// ---------------- K2: gap sums + 1x1 base + biases + up(ms) -> out (4 px/thread) ----------------
__global__ __launch_bounds__(256) void k_base(const float* __restrict__ feat,
                                              const float* __restrict__ ms,
                                              const float* __restrict__ w_res,
                                              const float* __restrict__ b_fine,
                                              const float* __restrict__ b_res,
                                              float* __restrict__ gap,
                                              float* __restrict__ out) {
    int gid = blockIdx.x;                         // 0..511
    int tid = threadIdx.x;
    int b = gid >> 4, strip = gid & 15;
    int row = (strip << 3) + (tid >> 5);
    int x0  = (tid & 31) << 2;
    int poff = (row << 7) + x0;
    int lane = tid & 63;
    const float* fb = feat + (((size_t)b * NFEAT) << 14);
    float a[4][4];
#pragma unroll
    for (int j = 0; j < 4; ++j)
#pragma unroll
        for (int o = 0; o < 4; ++o) a[j][o] = 0.f;
    for (int c = 0; c < NFEAT; ++c) {
        float4 f = *(const float4*)&fb[((size_t)c << 14) + poff];
        float wr0 = w_res[c], wr1 = w_res[NFEAT + c];
        float wr2 = w_res[2 * NFEAT + c], wr3 = w_res[3 * NFEAT + c];
        a[0][0] += wr0 * f.x; a[0][1] += wr1 * f.x; a[0][2] += wr2 * f.x; a[0][3] += wr3 * f.x;
        a[1][0] += wr0 * f.y; a[1][1] += wr1 * f.y; a[1][2] += wr2 * f.y; a[1][3] += wr3 * f.y;
        a[2][0] += wr0 * f.z; a[2][1] += wr1 * f.z; a[2][2] += wr2 * f.z; a[2][3] += wr3 * f.z;
        a[3][0] += wr0 * f.w; a[3][1] += wr1 * f.w; a[3][2] += wr2 * f.w; a[3][3] += wr3 * f.w;
        if (c >= C1c) {
            float s = (f.x + f.y) + (f.z + f.w);
            s += __shfl_xor(s, 1);  s += __shfl_xor(s, 2);  s += __shfl_xor(s, 4);
            s += __shfl_xor(s, 8);  s += __shfl_xor(s, 16); s += __shfl_xor(s, 32);
            if (lane == 0) atomicAdd(&gap[b * LRC + (c - C1c)], s);
        }
    }
    float syf = (row + 0.5f) * 0.25f - 0.5f;
    int y0i = (int)floorf(syf); float fy = syf - (float)y0i;
    int y0c = min(31, max(0, y0i)), y1c = min(31, max(0, y0i + 1));
    float fxv[4]; int x0v[4], x1v[4];
#pragma unroll
    for (int j = 0; j < 4; ++j) {
        float sxf = (x0 + j + 0.5f) * 0.25f - 0.5f;
        int x0i = (int)floorf(sxf);
        fxv[j] = sxf - (float)x0i;
        x0v[j] = min(31, max(0, x0i));
        x1v[j] = min(31, max(0, x0i + 1));
    }
#pragma unroll
    for (int o = 0; o < 4; ++o) {
        const float* mb = ms + ((size_t)(b * 4 + o) << 10);
        float addc = b_fine[o] + b_res[o];
        float res[4];
#pragma unroll
        for (int j = 0; j < 4; ++j) {
            float m00 = mb[(y0c << 5) + x0v[j]], m01 = mb[(y0c << 5) + x1v[j]];
            float m10 = mb[(y1c << 5) + x0v[j]], m11 = mb[(y1c << 5) + x1v[j]];
            float up = (m00 * (1.f - fxv[j]) + m01 * fxv[j]) * (1.f - fy)
                     + (m10 * (1.f - fxv[j]) + m11 * fxv[j]) * fy;
            res[j] = a[j][o] + addc + up;
        }
        *(float4*)&out[(((size_t)(b * 4 + o)) << 14) + poff] =
            make_float4(res[0], res[1], res[2], res[3]);
    }
}

// ---------------- K1b: binning pass -> pm_sum[81][64] ----------------
__global__ __launch_bounds__(256) void k_sm2(const float* __restrict__ logits,
                                             const float* __restrict__ invbuf,
                                             float* __restrict__ pm_sum) {
    int bid = blockIdx.x;                 // b*81 + p
    int b = bid / NP, p = bid - b * NP;
    const float* base = logits + ((size_t)(b * NP + p) << 14);
    const float* ib   = invbuf + ((size_t)b << 14);
    int tid = threadIdx.x;
    int r0 = tid >> 5, xt = tid & 31;
    float a0 = 0.f, a1 = 0.f, a2 = 0.f, a3 = 0.f;
    int off = (r0 << 7) + (xt << 2);
#pragma unroll 4
    for (int k = 0; k < 16; ++k) {
        int o2 = off + k * 1024;
        float4 l4 = *(const float4*)&base[o2];
        float4 i4 = *(const float4*)&ib[o2];
        a0 += __expf(l4.x) * i4.x;
        a1 += __expf(l4.y) * i4.y;
        a2 += __expf(l4.z) * i4.z;
        a3 += __expf(l4.w) * i4.w;
    }
#pragma unroll
    for (int m = 2; m <= 16; m <<= 1) {
        a0 += __shfl_xor(a0, m); a1 += __shfl_xor(a1, m);
        a2 += __shfl_xor(a2, m); a3 += __shfl_xor(a3, m);
    }
    if (xt < 2) {
        int qb = p * NQ + (r0 << 3) + ((xt & 1) << 2);
        atomicAdd(&pm_sum[qb + 0], a0);
        atomicAdd(&pm_sum[qb + 1], a1);
        atomicAdd(&pm_sum[qb + 2], a2);
        atomicAdd(&pm_sum[qb + 3], a3);
    }
}

// ---------------- K3: build K (64x64), attn (32x42), rearranged weights wbuf[48][48] ----------------
__global__ __launch_bounds__(256) void k_small(const float* __restrict__ pm_sum,
                                               const float* __restrict__ gap_sum,
                                               const float* __restrict__ sigx,
                                               const float* __restrict__ sigy,
                                               const float* __restrict__ opac,
                                               const float* __restrict__ rho,
                                               const float* __restrict__ w_v2,
                                               const float* __restrict__ w_fine,
                                               const float* __restrict__ w_res,
                                               float* __restrict__ Kmat,
                                               float* __restrict__ attn,
                                               float* __restrict__ wbuf) {
    int tid = threadIdx.x;
    if (tid < 64) {
        int q = tid;
        float wsx = 0.f, wsy = 0.f, wop = 0.f, wr = 0.f;
        for (int p = 0; p < NP; ++p) {
            float pv = pm_sum[p * NQ + q] * (1.f / 8192.f);
            wsx += sigx[p] * pv;
            wsy += sigy[p] * pv;
            wop += opac[p] * pv;
            wr  += rho[p]  * pv;
        }
        float a = wsx * wsx, d = wsy * wsy, bc = wr * wsx * wsy;
        float det = a * d - bc * bc;
        float i00 = d / det, i01 = -bc / det, i11 = a / det;
        int iq = q >> 3, jq = q & 7;
        for (int h = 0; h < 8; ++h)
            for (int w = 0; w < 8; ++w) {
                int ki = h - iq + 2, kj = w - jq + 2;
                float val = 0.f;
                if (ki >= 0 && ki < 5 && kj >= 0 && kj < 5) {
                    float xx = -5.f + 2.5f * ki, yy = -5.f + 2.5f * kj;
                    val = wop * __expf(-0.5f * (i00 * xx * xx + 2.f * i01 * xx * yy + i11 * yy * yy));
                }
                Kmat[(q << 6) + (h << 3) + w] = val;
            }
    }
    for (int i = tid; i < NBATCH * LRC; i += 256) {
        int b = i / LRC, co = i % LRC;
        float s = 0.f;
        for (int ci = 0; ci < LRC; ++ci) s += w_v2[co * LRC + ci] * gap_sum[b * LRC + ci];
        s *= (1.f / 16384.f);
        attn[i] = 1.f / (1.f + __expf(-s));
    }
    for (int i = tid; i < NFEAT * 48; i += 256) {
        int c = i / 48, j = i - c * 48;
        float v = 0.f;
        if (j < 36) v = w_fine[(j / 9) * (NFEAT * 9) + c * 9 + (j % 9)];
        else if (j < 40) v = w_res[(j - 36) * NFEAT + c];
        wbuf[i] = v;
    }
}

// ---------------- K4: hr = (colors @ K) * V1 ----------------
__global__ __launch_bounds__(256) void k_hr(const float* __restrict__ feat,
                                            const float* __restrict__ V,
                                            const float* __restrict__ Kmat,
                                            float* __restrict__ hrbuf) {
    __shared__ __align__(16) float lK[4096];          // [q][pos] packed; reads broadcast
    __shared__ __align__(16) float lF[2 * 16 * 128];
    int bid = blockIdx.x;
    int b   = bid / 24;
    int r   = bid - b * 24;
    int strip = r / 3;
    int ch  = (r - strip * 3) * 2;
    int y0  = strip << 4;
    int tid = threadIdx.x;
    {
        const float4* ks = (const float4*)Kmat;
        float4* kd = (float4*)lK;
        for (int i = tid; i < 1024; i += 256) kd[i] = ks[i];
        float4* fd = (float4*)lF;
        const float* fb = feat + (((size_t)b * NFEAT + ch) << 14) + (y0 << 7);
        for (int i = tid; i < 1024; i += 256) {
            int c = i >> 9, rem = i & 511;
            fd[i] = *(const float4*)&fb[((size_t)c << 14) + (rem << 2)];
        }
    }
    __syncthreads();
    int tile = tid >> 3, hrow = tid & 7;
    int tr = tile >> 4, tx = tile & 15;
    float acc[2][8];
#pragma unroll
    for (int c = 0; c < 2; ++c)
#pragma unroll
        for (int j = 0; j < 8; ++j) acc[c][j] = 0.f;
    int fbase = (tr << 3) * 128 + (tx << 3);
    for (int q = 0; q < 64; ++q) {
        int iq = q >> 3, jq = q & 7;
        const float4 k0 = *(const float4*)&lK[(q << 6) + (hrow << 3)];
        const float4 k1 = *(const float4*)&lK[(q << 6) + (hrow << 3) + 4];
#pragma unroll
        for (int c = 0; c < 2; ++c) {
            float col = lF[(c << 11) + fbase + (iq << 7) + jq];
            acc[c][0] += col * k0.x; acc[c][1] += col * k0.y;
            acc[c][2] += col * k0.z; acc[c][3] += col * k0.w;
            acc[c][4] += col * k1.x; acc[c][5] += col * k1.y;
            acc[c][6] += col * k1.z; acc[c][7] += col * k1.w;
        }
    }
    int y = y0 + (tr << 3) + hrow;
#pragma unroll
    for (int c = 0; c < 2; ++c) {
        const float4* vp = (const float4*)(V + (((size_t)b * NFEAT + ch + c) << 14) + ((size_t)y << 7) + (tx << 3));
        float4 v0 = vp[0], v1 = vp[1];
        float4 r0, r1;
        r0.x = acc[c][0] * v0.x; r0.y = acc[c][1] * v0.y; r0.z = acc[c][2] * v0.z; r0.w = acc[c][3] * v0.w;
        r1.x = acc[c][4] * v1.x; r1.y = acc[c][5] * v1.y; r1.z = acc[c][6] * v1.z; r1.w = acc[c][7] * v1.w;
        float4* op = (float4*)(hrbuf + (((size_t)b * C1c + ch + c) << 14) + ((size_t)y << 7) + (tx << 3));
        op[0] = r0; op[1] = r1;
    }
}

// ---------------- K5: conv3x3 (RMW onto base), double-buffered LDS + reg-staged prefetch ----
#define CHN 6
__global__ __launch_bounds__(512, 4) void k_conv(const float* __restrict__ feat,
                                                 const float* __restrict__ V,
                                                 const float* __restrict__ wbuf,
                                                 const float* __restrict__ hrbuf,
                                                 const float* __restrict__ attn,
                                                 float* __restrict__ out) {
    __shared__ float s_in[2][CHN][18 * 40];   // 34.5 KB
    int bid0 = blockIdx.x;
    int rid  = (bid0 & 7) * 128 + (bid0 >> 3);    // bijective XCD swizzle (1024 = 8*128)
    int b    = rid >> 5;
    int t32  = rid & 31;
    int ty0  = (t32 >> 2) << 4;
    int tx0  = (t32 & 3) << 5;
    int tid  = threadIdx.x;               // 0..511
    int grpu = __builtin_amdgcn_readfirstlane(tid >> 8);   // 0/1, wave-uniform
    int ct   = tid & 255;
    int rp   = ct >> 5;                   // 0..7 (row pair)
    int j    = ct & 31;                   // col 0..31
    int gx   = tx0 + j;
    int gy0  = ty0 + 2 * rp;
    int cbase = (2 * rp) * 40 + 3 + j;

    // staging own pixel (1 px per thread over the 16x32 tile)
    int srow = tid >> 5, scol = tid & 31;
    int sg = ((ty0 + srow) << 7) + tx0 + scol;
    int sl = (srow + 1) * 40 + 4 + scol;

    // halo ring: 100 positions
    bool hhas = tid < 100;
    int rr, cc;
    if (tid < 34)      { rr = 0;        cc = tid; }
    else if (tid < 68) { rr = 17;       cc = tid - 34; }
    else if (tid < 84) { rr = tid - 67; cc = 0; }
    else               { rr = tid - 83; cc = 33; }
    int hsy = ty0 - 1 + rr, hsx = tx0 - 1 + cc;
    float hfm = (hsy >= 0 && hsy < HH && hsx >= 0 && hsx < WW) ? 1.f : 0.f;
    int hoff = (min(HH - 1, max(0, hsy)) << 7) + min(WW - 1, max(0, hsx));
    int hlds = rr * 40 + 3 + cc;

    const float* atb = attn + b * LRC;
    float a0[4] = {0.f, 0.f, 0.f, 0.f};
    float a1[4] = {0.f, 0.f, 0.f, 0.f};
    float rA[CHN], rB[CHN], rHA[CHN], rHB[CHN], amv[CHN];

    // ---- prologue: chunk 0 = hr channels 0..5 (pure copy) ----
#pragma unroll
    for (int k = 0; k < CHN; ++k) {
        const float* hs = hrbuf + (((size_t)(b * C1c + k)) << 14);
        rA[k]  = hs[sg];
        rHA[k] = hhas ? hs[hoff] : 0.f;
    }
#pragma unroll
    for (int k = 0; k < CHN; ++k) {
        s_in[0][k][sl] = rA[k];
        if (hhas) s_in[0][k][hlds] = rHA[k] * hfm;
    }
    int cur = 0;
    for (int t = 0; t < 8; ++t) {
        __syncthreads();
        // ---- issue next chunk's loads (channels 6(t+1)..6(t+1)+5, always feat*V) ----
        if (t < 7) {
            int c0 = CHN * (t + 1);
#pragma unroll
            for (int k = 0; k < CHN; ++k) {
                int c = c0 + k;
                const float* fs = feat + (((size_t)(b * NFEAT + c)) << 14);
                const float* vs = V    + (((size_t)(b * NFEAT + c)) << 14);
                rA[k] = fs[sg];
                rB[k] = vs[sg];
                amv[k] = atb[c - C1c];
                rHA[k] = hhas ? fs[hoff] : 0.f;
                rHB[k] = hhas ? vs[hoff] : 0.f;
            }
        }
        // ---- compute current chunk (hides the loads above) ----
        int c0c = CHN * t;
        for (int k = 0; k < 3; ++k) {
            int slot = 3 * grpu + k;
            int c = c0c + slot;
            const float* wc = wbuf + c * 48;          // uniform -> s_load
            const float* sp = &s_in[cur][slot][cbase];
            float t00 = sp[0],   t01 = sp[1],   t02 = sp[2];
            float t10 = sp[40],  t11 = sp[41],  t12 = sp[42];
            float t20 = sp[80],  t21 = sp[81],  t22 = sp[82];
            float t30 = sp[120], t31 = sp[121], t32 = sp[122];
#pragma unroll
            for (int o = 0; o < 4; ++o) {
                float w0 = wc[o * 9 + 0], w1 = wc[o * 9 + 1], w2 = wc[o * 9 + 2];
                float w3 = wc[o * 9 + 3], w4 = wc[o * 9 + 4], w5 = wc[o * 9 + 5];
                float w6 = wc[o * 9 + 6], w7 = wc[o * 9 + 7], w8 = wc[o * 9 + 8];
                a0[o] += w0 * t00 + w1 * t01 + w2 * t02
                       + w3 * t10 + w4 * t11 + w5 * t12
                       + w6 * t20 + w7 * t21 + w8 * t22;
                a1[o] += w0 * t10 + w1 * t11 + w2 * t12
                       + w3 * t20 + w4 * t21 + w5 * t22
                       + w6 * t30 + w7 * t31 + w8 * t32;
            }
        }
        // ---- write prefetched chunk to the other buffer ----
        if (t < 7) {
            int nxt = cur ^ 1;
#pragma unroll
            for (int k = 0; k < CHN; ++k) {
                s_in[nxt][k][sl] = rA[k] * rB[k] * amv[k];
                if (hhas) s_in[nxt][k][hlds] = rHA[k] * rHB[k] * (amv[k] * hfm);
            }
        }
        cur ^= 1;
    }
    // ---- merge group1 -> group0, then RMW stores (group0 only) ----
    __syncthreads();
    float* sm = &s_in[0][0][0];                  // reuse LDS (2048 floats needed)
    int p0 = (2 * rp) * 32 + j, p1 = p0 + 32;
    if (grpu == 1) {
#pragma unroll
        for (int o = 0; o < 4; ++o) { sm[o * 512 + p0] = a0[o]; sm[o * 512 + p1] = a1[o]; }
    }
    __syncthreads();
    if (grpu == 0) {
#pragma unroll
        for (int o = 0; o < 4; ++o) {
            size_t obase = ((size_t)(b * 4 + o)) << 14;
            float* op0 = out + obase + (gy0 << 7) + gx;
            float* op1 = out + obase + ((gy0 + 1) << 7) + gx;
            *op0 = *op0 + a0[o] + sm[o * 512 + p0];
            *op1 = *op1 + a1[o] + sm[o * 512 + p1];
        }
    }
}

extern "C" void kernel_launch(void* const* d_in, const int* in_sizes, int n_in,
                              void* d_out, int out_size, void* d_ws, size_t ws_size,
                              hipStream_t stream) {
    (void)in_sizes; (void)n_in; (void)out_size; (void)ws_size;
    const float* ms     = (const float*)d_in[0];
    const float* feat   = (const float*)d_in[1];
    const float* V      = (const float*)d_in[2];
    const float* logits = (const float*)d_in[3];
    const float* sigx   = (const float*)d_in[4];
    const float* sigy   = (const float*)d_in[5];
    const float* opac   = (const float*)d_in[6];
    const float* rho    = (const float*)d_in[7];
    const float* w_v2   = (const float*)d_in[8];
    const float* w_fine = (const float*)d_in[9];
    const float* b_fine = (const float*)d_in[10];
    const float* w_res  = (const float*)d_in[11];
    const float* b_res  = (const float*)d_in[12];
    float* ws  = (float*)d_ws;
    float* out = (float*)d_out;
    float* inv  = ws + OFF_HR;    // 524288 floats; consumed by k_sm2 before k_hr overwrites
    float* part = ws + OFF_PART;  // 4718592 floats, beyond hr region (ws is ~650 MB)

    // zero pm_sum + gap
    hipMemsetAsync(ws + OFF_PM, 0, (size_t)(NP * NQ + NBATCH * LRC) * sizeof(float), stream);
    k_sm1<<<288, 256, 0, stream>>>(logits, part);
    k_base<<<512, 256, 0, stream>>>(feat, ms, w_res, b_fine, b_res, ws + OFF_GAP, out);
    k_minv<<<512, 256, 0, stream>>>(part, inv);
    k_sm2<<<NBATCH * NP, 256, 0, stream>>>(logits, inv, ws + OFF_PM);
    k_small<<<1, 256, 0, stream>>>(ws + OFF_PM, ws + OFF_GAP, sigx, sigy, opac, rho, w_v2,
                                   w_fine, w_res, ws + OFF_K, ws + OFF_ATTN, ws + OFF_WB);
    k_hr<<<768, 256, 0, stream>>>(feat, V, ws + OFF_K, ws + OFF_HR);
    k_conv<<<1024, 512, 0, stream>>>(feat, V, ws + OFF_WB, ws + OFF_HR, ws + OFF_ATTN, out);
}

// Round 20
// 210.313 us; speedup vs baseline: 1.3131x; 1.3131x over previous
//
#include <hip/hip_runtime.h>

#define NBATCH 32
#define NFEAT 48
#define C1c 6
#define LRC 42
#define HH 128
#define WW 128
#define HWSZ 16384
#define NP 81
#define NQ 64

// workspace layout (in floats)
#define OFF_PM   0                      // 81*64 = 5184
#define OFF_GAP  5184                   // 32*42 = 1344
#define OFF_K    6528                   // 64*64 = 4096
#define OFF_ATTN 10624                  // 1344
#define OFF_WB   11968                  // 48*48 = 2304 rearranged weights
#define OFF_HR   14272                  // 32*6*16384 = 3145728 (hrbuf; inv reuses it pre-k_hr)
#define OFF_PART (OFF_HR + 4194304)     // 3 * 524288 partial sums

typedef float f4 __attribute__((ext_vector_type(4)));

#define GL(dst, ptr) asm volatile("global_load_dwordx4 %0, %1, off" : "=v"(dst) : "v"(ptr))
#define WAITV2()     asm volatile("s_waitcnt vmcnt(2)" ::: "memory")
#define WAITV0()     asm volatile("s_waitcnt vmcnt(0)" ::: "memory")
#define SBAR()       __builtin_amdgcn_sched_barrier(0)

// ---------------- Phase 1 (heterogeneous):
//   bid <  768: softmax partial denominators, asm-pipelined loads (3 p-chunks x 32 b x 8 windows)
//   bid >= 768: gap sums + 1x1 base + biases + up(ms) -> out ----------------
__global__ __launch_bounds__(256) void k_phase1(const float* __restrict__ logits,
                                                const float* __restrict__ feat,
                                                const float* __restrict__ ms,
                                                const float* __restrict__ w_res,
                                                const float* __restrict__ b_fine,
                                                const float* __restrict__ b_res,
                                                float* __restrict__ part,
                                                float* __restrict__ gap,
                                                float* __restrict__ out) {
    int bid = blockIdx.x;
    int tid = threadIdx.x;
    if (bid < 768) {
        int s = bid >> 8;                 // p-chunk 0..2 (27 planes each)
        int r = bid & 255;
        int b = r >> 3, w = r & 7;        // image, window of 2048 px
        const float* base = logits + (((size_t)(b * NP + s * 27)) << 14) + (w << 11) + (tid << 3);
        f4 A0 = {0.f, 0.f, 0.f, 0.f}, A1 = {0.f, 0.f, 0.f, 0.f};
        f4 c0, c1, n0, n1;
        GL(c0, base); GL(c1, base + 4);
        for (int p = 0; p < 26; p += 2) {
            const float* p1 = base + ((size_t)(p + 1) << 14);
            GL(n0, p1); GL(n1, p1 + 4);
            WAITV2(); SBAR();
            A0.x += __expf(c0.x); A0.y += __expf(c0.y); A0.z += __expf(c0.z); A0.w += __expf(c0.w);
            A1.x += __expf(c1.x); A1.y += __expf(c1.y); A1.z += __expf(c1.z); A1.w += __expf(c1.w);
            const float* p2 = base + ((size_t)(p + 2) << 14);
            GL(c0, p2); GL(c1, p2 + 4);
            WAITV2(); SBAR();
            A0.x += __expf(n0.x); A0.y += __expf(n0.y); A0.z += __expf(n0.z); A0.w += __expf(n0.w);
            A1.x += __expf(n1.x); A1.y += __expf(n1.y); A1.z += __expf(n1.z); A1.w += __expf(n1.w);
        }
        WAITV0(); SBAR();
        A0.x += __expf(c0.x); A0.y += __expf(c0.y); A0.z += __expf(c0.z); A0.w += __expf(c0.w);
        A1.x += __expf(c1.x); A1.y += __expf(c1.y); A1.z += __expf(c1.z); A1.w += __expf(c1.w);
        float* pp = part + (size_t)s * 524288 + ((size_t)b << 14) + (w << 11) + (tid << 3);
        *(f4*)pp = A0;
        *(f4*)(pp + 4) = A1;
    } else {
        // ---- base: gap sums + 1x1 + biases + up(ms) -> out (4 px/thread) ----
        int gid = bid - 768;                          // 0..511
        int b = gid >> 4, strip = gid & 15;
        int row = (strip << 3) + (tid >> 5);
        int x0  = (tid & 31) << 2;
        int poff = (row << 7) + x0;
        int lane = tid & 63;
        const float* fb = feat + (((size_t)b * NFEAT) << 14);
        float a[4][4];
#pragma unroll
        for (int j = 0; j < 4; ++j)
#pragma unroll
            for (int o = 0; o < 4; ++o) a[j][o] = 0.f;
        for (int c = 0; c < NFEAT; ++c) {
            float4 f = *(const float4*)&fb[((size_t)c << 14) + poff];
            float wr0 = w_res[c], wr1 = w_res[NFEAT + c];
            float wr2 = w_res[2 * NFEAT + c], wr3 = w_res[3 * NFEAT + c];
            a[0][0] += wr0 * f.x; a[0][1] += wr1 * f.x; a[0][2] += wr2 * f.x; a[0][3] += wr3 * f.x;
            a[1][0] += wr0 * f.y; a[1][1] += wr1 * f.y; a[1][2] += wr2 * f.y; a[1][3] += wr3 * f.y;
            a[2][0] += wr0 * f.z; a[2][1] += wr1 * f.z; a[2][2] += wr2 * f.z; a[2][3] += wr3 * f.z;
            a[3][0] += wr0 * f.w; a[3][1] += wr1 * f.w; a[3][2] += wr2 * f.w; a[3][3] += wr3 * f.w;
            if (c >= C1c) {
                float s = (f.x + f.y) + (f.z + f.w);
                s += __shfl_xor(s, 1);  s += __shfl_xor(s, 2);  s += __shfl_xor(s, 4);
                s += __shfl_xor(s, 8);  s += __shfl_xor(s, 16); s += __shfl_xor(s, 32);
                if (lane == 0) atomicAdd(&gap[b * LRC + (c - C1c)], s);
            }
        }
        float syf = (row + 0.5f) * 0.25f - 0.5f;
        int y0i = (int)floorf(syf); float fy = syf - (float)y0i;
        int y0c = min(31, max(0, y0i)), y1c = min(31, max(0, y0i + 1));
        float fxv[4]; int x0v[4], x1v[4];
#pragma unroll
        for (int j = 0; j < 4; ++j) {
            float sxf = (x0 + j + 0.5f) * 0.25f - 0.5f;
            int x0i = (int)floorf(sxf);
            fxv[j] = sxf - (float)x0i;
            x0v[j] = min(31, max(0, x0i));
            x1v[j] = min(31, max(0, x0i + 1));
        }
#pragma unroll
        for (int o = 0; o < 4; ++o) {
            const float* mb = ms + ((size_t)(b * 4 + o) << 10);
            float addc = b_fine[o] + b_res[o];
            float res[4];
#pragma unroll
            for (int j = 0; j < 4; ++j) {
                float m00 = mb[(y0c << 5) + x0v[j]], m01 = mb[(y0c << 5) + x1v[j]];
                float m10 = mb[(y1c << 5) + x0v[j]], m11 = mb[(y1c << 5) + x1v[j]];
                float up = (m00 * (1.f - fxv[j]) + m01 * fxv[j]) * (1.f - fy)
                         + (m10 * (1.f - fxv[j]) + m11 * fxv[j]) * fy;
                res[j] = a[j][o] + addc + up;
            }
            *(float4*)&out[(((size_t)(b * 4 + o)) << 14) + poff] =
                make_float4(res[0], res[1], res[2], res[3]);
        }
    }
}

// ---------------- K1a': merge 3 partials -> inv (at OFF_HR) ----------------
__global__ __launch_bounds__(256) void k_minv(const float* __restrict__ part,
                                              float* __restrict__ invbuf) {
    int idx = blockIdx.x * 256 + threadIdx.x;     // 0..131071 (f4 index)
    const f4* p4 = (const f4*)part;
    f4 a = p4[idx];
    f4 b = p4[idx + 131072];
    f4 c = p4[idx + 262144];
    f4 s = a + b + c;
    f4 r = {1.f / s.x, 1.f / s.y, 1.f / s.z, 1.f / s.w};
    ((f4*)invbuf)[idx] = r;
}

// ---------------- K1b: binning pass -> pm_sum[81][64] (logits L3-warm from phase1) ----------------
__global__ __launch_bounds__(256) void k_sm2(const float* __restrict__ logits,
                                             const float* __restrict__ invbuf,
                                             float* __restrict__ pm_sum) {
    int bid = blockIdx.x;                 // b*81 + p
    int b = bid / NP, p = bid - b * NP;
    const float* base = logits + ((size_t)(b * NP + p) << 14);
    const float* ib   = invbuf + ((size_t)b << 14);
    int tid = threadIdx.x;
    int r0 = tid >> 5, xt = tid & 31;
    float a0 = 0.f, a1 = 0.f, a2 = 0.f, a3 = 0.f;
    int off = (r0 << 7) + (xt << 2);
#pragma unroll 4
    for (int k = 0; k < 16; ++k) {
        int o2 = off + k * 1024;
        float4 l4 = *(const float4*)&base[o2];
        float4 i4 = *(const float4*)&ib[o2];
        a0 += __expf(l4.x) * i4.x;
        a1 += __expf(l4.y) * i4.y;
        a2 += __expf(l4.z) * i4.z;
        a3 += __expf(l4.w) * i4.w;
    }
#pragma unroll
    for (int m = 2; m <= 16; m <<= 1) {
        a0 += __shfl_xor(a0, m); a1 += __shfl_xor(a1, m);
        a2 += __shfl_xor(a2, m); a3 += __shfl_xor(a3, m);
    }
    if (xt < 2) {
        int qb = p * NQ + (r0 << 3) + ((xt & 1) << 2);
        atomicAdd(&pm_sum[qb + 0], a0);
        atomicAdd(&pm_sum[qb + 1], a1);
        atomicAdd(&pm_sum[qb + 2], a2);
        atomicAdd(&pm_sum[qb + 3], a3);
    }
}

// ---------------- K3: build K (64x64), attn (32x42), rearranged weights wbuf[48][48] ----------------
__global__ __launch_bounds__(256) void k_small(const float* __restrict__ pm_sum,
                                               const float* __restrict__ gap_sum,
                                               const float* __restrict__ sigx,
                                               const float* __restrict__ sigy,
                                               const float* __restrict__ opac,
                                               const float* __restrict__ rho,
                                               const float* __restrict__ w_v2,
                                               const float* __restrict__ w_fine,
                                               const float* __restrict__ w_res,
                                               float* __restrict__ Kmat,
                                               float* __restrict__ attn,
                                               float* __restrict__ wbuf) {
    int tid = threadIdx.x;
    if (tid < 64) {
        int q = tid;
        float wsx = 0.f, wsy = 0.f, wop = 0.f, wr = 0.f;
        for (int p = 0; p < NP; ++p) {
            float pv = pm_sum[p * NQ + q] * (1.f / 8192.f);
            wsx += sigx[p] * pv;
            wsy += sigy[p] * pv;
            wop += opac[p] * pv;
            wr  += rho[p]  * pv;
        }
        float a = wsx * wsx, d = wsy * wsy, bc = wr * wsx * wsy;
        float det = a * d - bc * bc;
        float i00 = d / det, i01 = -bc / det, i11 = a / det;
        int iq = q >> 3, jq = q & 7;
        for (int h = 0; h < 8; ++h)
            for (int w = 0; w < 8; ++w) {
                int ki = h - iq + 2, kj = w - jq + 2;
                float val = 0.f;
                if (ki >= 0 && ki < 5 && kj >= 0 && kj < 5) {
                    float xx = -5.f + 2.5f * ki, yy = -5.f + 2.5f * kj;
                    val = wop * __expf(-0.5f * (i00 * xx * xx + 2.f * i01 * xx * yy + i11 * yy * yy));
                }
                Kmat[(q << 6) + (h << 3) + w] = val;
            }
    }
    for (int i = tid; i < NBATCH * LRC; i += 256) {
        int b = i / LRC, co = i % LRC;
        float s = 0.f;
        for (int ci = 0; ci < LRC; ++ci) s += w_v2[co * LRC + ci] * gap_sum[b * LRC + ci];
        s *= (1.f / 16384.f);
        attn[i] = 1.f / (1.f + __expf(-s));
    }
    for (int i = tid; i < NFEAT * 48; i += 256) {
        int c = i / 48, j = i - c * 48;
        float v = 0.f;
        if (j < 36) v = w_fine[(j / 9) * (NFEAT * 9) + c * 9 + (j % 9)];
        else if (j < 40) v = w_res[(j - 36) * NFEAT + c];
        wbuf[i] = v;
    }
}

// ---------------- K4: hr = (colors @ K) * V1 ----------------
__global__ __launch_bounds__(256) void k_hr(const float* __restrict__ feat,
                                            const float* __restrict__ V,
                                            const float* __restrict__ Kmat,
                                            float* __restrict__ hrbuf) {
    __shared__ __align__(16) float lK[4096];
    __shared__ __align__(16) float lF[2 * 16 * 128];
    int bid = blockIdx.x;
    int b   = bid / 24;
    int r   = bid - b * 24;
    int strip = r / 3;
    int ch  = (r - strip * 3) * 2;
    int y0  = strip << 4;
    int tid = threadIdx.x;
    {
        const float4* ks = (const float4*)Kmat;
        float4* kd = (float4*)lK;
        for (int i = tid; i < 1024; i += 256) kd[i] = ks[i];
        float4* fd = (float4*)lF;
        const float* fb = feat + (((size_t)b * NFEAT + ch) << 14) + (y0 << 7);
        for (int i = tid; i < 1024; i += 256) {
            int c = i >> 9, rem = i & 511;
            fd[i] = *(const float4*)&fb[((size_t)c << 14) + (rem << 2)];
        }
    }
    __syncthreads();
    int tile = tid >> 3, hrow = tid & 7;
    int tr = tile >> 4, tx = tile & 15;
    float acc[2][8];
#pragma unroll
    for (int c = 0; c < 2; ++c)
#pragma unroll
        for (int j = 0; j < 8; ++j) acc[c][j] = 0.f;
    int fbase = (tr << 3) * 128 + (tx << 3);
    for (int q = 0; q < 64; ++q) {
        int iq = q >> 3, jq = q & 7;
        const float4 k0 = *(const float4*)&lK[(q << 6) + (hrow << 3)];
        const float4 k1 = *(const float4*)&lK[(q << 6) + (hrow << 3) + 4];
#pragma unroll
        for (int c = 0; c < 2; ++c) {
            float col = lF[(c << 11) + fbase + (iq << 7) + jq];
            acc[c][0] += col * k0.x; acc[c][1] += col * k0.y;
            acc[c][2] += col * k0.z; acc[c][3] += col * k0.w;
            acc[c][4] += col * k1.x; acc[c][5] += col * k1.y;
            acc[c][6] += col * k1.z; acc[c][7] += col * k1.w;
        }
    }
    int y = y0 + (tr << 3) + hrow;
#pragma unroll
    for (int c = 0; c < 2; ++c) {
        const float4* vp = (const float4*)(V + (((size_t)b * NFEAT + ch + c) << 14) + ((size_t)y << 7) + (tx << 3));
        float4 v0 = vp[0], v1 = vp[1];
        float4 r0, r1;
        r0.x = acc[c][0] * v0.x; r0.y = acc[c][1] * v0.y; r0.z = acc[c][2] * v0.z; r0.w = acc[c][3] * v0.w;
        r1.x = acc[c][4] * v1.x; r1.y = acc[c][5] * v1.y; r1.z = acc[c][6] * v1.z; r1.w = acc[c][7] * v1.w;
        float4* op = (float4*)(hrbuf + (((size_t)b * C1c + ch + c) << 14) + ((size_t)y << 7) + (tx << 3));
        op[0] = r0; op[1] = r1;
    }
}

// ---------------- K5: conv3x3 (RMW onto base), double-buffered LDS + reg-staged prefetch ----
#define CHN 6
__global__ __launch_bounds__(512, 4) void k_conv(const float* __restrict__ feat,
                                                 const float* __restrict__ V,
                                                 const float* __restrict__ wbuf,
                                                 const float* __restrict__ hrbuf,
                                                 const float* __restrict__ attn,
                                                 float* __restrict__ out) {
    __shared__ float s_in[2][CHN][18 * 40];   // 34.5 KB
    int bid0 = blockIdx.x;
    int rid  = (bid0 & 7) * 128 + (bid0 >> 3);
    int b    = rid >> 5;
    int t32  = rid & 31;
    int ty0  = (t32 >> 2) << 4;
    int tx0  = (t32 & 3) << 5;
    int tid  = threadIdx.x;
    int grpu = __builtin_amdgcn_readfirstlane(tid >> 8);
    int ct   = tid & 255;
    int rp   = ct >> 5;
    int j    = ct & 31;
    int gx   = tx0 + j;
    int gy0  = ty0 + 2 * rp;
    int cbase = (2 * rp) * 40 + 3 + j;

    int srow = tid >> 5, scol = tid & 31;
    int sg = ((ty0 + srow) << 7) + tx0 + scol;
    int sl = (srow + 1) * 40 + 4 + scol;

    bool hhas = tid < 100;
    int rr, cc;
    if (tid < 34)      { rr = 0;        cc = tid; }
    else if (tid < 68) { rr = 17;       cc = tid - 34; }
    else if (tid < 84) { rr = tid - 67; cc = 0; }
    else               { rr = tid - 83; cc = 33; }
    int hsy = ty0 - 1 + rr, hsx = tx0 - 1 + cc;
    float hfm = (hsy >= 0 && hsy < HH && hsx >= 0 && hsx < WW) ? 1.f : 0.f;
    int hoff = (min(HH - 1, max(0, hsy)) << 7) + min(WW - 1, max(0, hsx));
    int hlds = rr * 40 + 3 + cc;

    const float* atb = attn + b * LRC;
    float a0[4] = {0.f, 0.f, 0.f, 0.f};
    float a1[4] = {0.f, 0.f, 0.f, 0.f};
    float rA[CHN], rB[CHN], rHA[CHN], rHB[CHN], amv[CHN];

#pragma unroll
    for (int k = 0; k < CHN; ++k) {
        const float* hs = hrbuf + (((size_t)(b * C1c + k)) << 14);
        rA[k]  = hs[sg];
        rHA[k] = hhas ? hs[hoff] : 0.f;
    }
#pragma unroll
    for (int k = 0; k < CHN; ++k) {
        s_in[0][k][sl] = rA[k];
        if (hhas) s_in[0][k][hlds] = rHA[k] * hfm;
    }
    int cur = 0;
    for (int t = 0; t < 8; ++t) {
        __syncthreads();
        if (t < 7) {
            int c0 = CHN * (t + 1);
#pragma unroll
            for (int k = 0; k < CHN; ++k) {
                int c = c0 + k;
                const float* fs = feat + (((size_t)(b * NFEAT + c)) << 14);
                const float* vs = V    + (((size_t)(b * NFEAT + c)) << 14);
                rA[k] = fs[sg];
                rB[k] = vs[sg];
                amv[k] = atb[c - C1c];
                rHA[k] = hhas ? fs[hoff] : 0.f;
                rHB[k] = hhas ? vs[hoff] : 0.f;
            }
        }
        int c0c = CHN * t;
        for (int k = 0; k < 3; ++k) {
            int slot = 3 * grpu + k;
            int c = c0c + slot;
            const float* wc = wbuf + c * 48;
            const float* sp = &s_in[cur][slot][cbase];
            float t00 = sp[0],   t01 = sp[1],   t02 = sp[2];
            float t10 = sp[40],  t11 = sp[41],  t12 = sp[42];
            float t20 = sp[80],  t21 = sp[81],  t22 = sp[82];
            float t30 = sp[120], t31 = sp[121], t32 = sp[122];
#pragma unroll
            for (int o = 0; o < 4; ++o) {
                float w0 = wc[o * 9 + 0], w1 = wc[o * 9 + 1], w2 = wc[o * 9 + 2];
                float w3 = wc[o * 9 + 3], w4 = wc[o * 9 + 4], w5 = wc[o * 9 + 5];
                float w6 = wc[o * 9 + 6], w7 = wc[o * 9 + 7], w8 = wc[o * 9 + 8];
                a0[o] += w0 * t00 + w1 * t01 + w2 * t02
                       + w3 * t10 + w4 * t11 + w5 * t12
                       + w6 * t20 + w7 * t21 + w8 * t22;
                a1[o] += w0 * t10 + w1 * t11 + w2 * t12
                       + w3 * t20 + w4 * t21 + w5 * t22
                       + w6 * t30 + w7 * t31 + w8 * t32;
            }
        }
        if (t < 7) {
            int nxt = cur ^ 1;
#pragma unroll
            for (int k = 0; k < CHN; ++k) {
                s_in[nxt][k][sl] = rA[k] * rB[k] * amv[k];
                if (hhas) s_in[nxt][k][hlds] = rHA[k] * rHB[k] * (amv[k] * hfm);
            }
        }
        cur ^= 1;
    }
    __syncthreads();
    float* sm = &s_in[0][0][0];
    int p0 = (2 * rp) * 32 + j, p1 = p0 + 32;
    if (grpu == 1) {
#pragma unroll
        for (int o = 0; o < 4; ++o) { sm[o * 512 + p0] = a0[o]; sm[o * 512 + p1] = a1[o]; }
    }
    __syncthreads();
    if (grpu == 0) {
#pragma unroll
        for (int o = 0; o < 4; ++o) {
            size_t obase = ((size_t)(b * 4 + o)) << 14;
            float* op0 = out + obase + (gy0 << 7) + gx;
            float* op1 = out + obase + ((gy0 + 1) << 7) + gx;
            *op0 = *op0 + a0[o] + sm[o * 512 + p0];
            *op1 = *op1 + a1[o] + sm[o * 512 + p1];
        }
    }
}

extern "C" void kernel_launch(void* const* d_in, const int* in_sizes, int n_in,
                              void* d_out, int out_size, void* d_ws, size_t ws_size,
                              hipStream_t stream) {
    (void)in_sizes; (void)n_in; (void)out_size; (void)ws_size;
    const float* ms     = (const float*)d_in[0];
    const float* feat   = (const float*)d_in[1];
    const float* V      = (const float*)d_in[2];
    const float* logits = (const float*)d_in[3];
    const float* sigx   = (const float*)d_in[4];
    const float* sigy   = (const float*)d_in[5];
    const float* opac   = (const float*)d_in[6];
    const float* rho    = (const float*)d_in[7];
    const float* w_v2   = (const float*)d_in[8];
    const float* w_fine = (const float*)d_in[9];
    const float* b_fine = (const float*)d_in[10];
    const float* w_res  = (const float*)d_in[11];
    const float* b_res  = (const float*)d_in[12];
    float* ws  = (float*)d_ws;
    float* out = (float*)d_out;
    float* inv  = ws + OFF_HR;    // consumed by k_sm2 before k_hr overwrites
    float* part = ws + OFF_PART;  // 3 x 524288 floats

    hipMemsetAsync(ws + OFF_PM, 0, (size_t)(NP * NQ + NBATCH * LRC) * sizeof(float), stream);
    k_phase1<<<768 + 512, 256, 0, stream>>>(logits, feat, ms, w_res, b_fine, b_res,
                                            part, ws + OFF_GAP, out);
    k_minv<<<512, 256, 0, stream>>>(part, inv);
    k_sm2<<<NBATCH * NP, 256, 0, stream>>>(logits, inv, ws + OFF_PM);
    k_small<<<1, 256, 0, stream>>>(ws + OFF_PM, ws + OFF_GAP, sigx, sigy, opac, rho, w_v2,
                                   w_fine, w_res, ws + OFF_K, ws + OFF_ATTN, ws + OFF_WB);
    k_hr<<<768, 256, 0, stream>>>(feat, V, ws + OFF_K, ws + OFF_HR);
    k_conv<<<1024, 512, 0, stream>>>(feat, V, ws + OFF_WB, ws + OFF_HR, ws + OFF_ATTN, out);
}

// Round 21
// 195.739 us; speedup vs baseline: 1.4108x; 1.0745x over previous
//
#include <hip/hip_runtime.h>

#define NBATCH 32
#define NFEAT 48
#define C1c 6
#define LRC 42
#define HH 128
#define WW 128
#define HWSZ 16384
#define NP 81
#define NQ 64

// workspace layout (in floats)
#define OFF_PM   0                      // 81*64 = 5184
#define OFF_GAP  5184                   // 32*42 = 1344  (contiguous after PM -> one memset)
#define OFF_K    6528                   // 64*64 = 4096
#define OFF_ATTN 10624                  // 1344
#define OFF_WB   11968                  // 48*48 = 2304 rearranged weights
#define OFF_HR   14272                  // 32*6*16384 = 3145728
// inv denominators (524288 floats) reuse the OFF_HR region: consumed by k_sm2 BEFORE k_hr writes.

// ---------------- Phase 1 (heterogeneous): A) softmax denominators  B) gap + 1x1 base + up(ms) ----
__global__ __launch_bounds__(256) void k_phase1(const float* __restrict__ logits,
                                                const float* __restrict__ feat,
                                                const float* __restrict__ ms,
                                                const float* __restrict__ w_res,
                                                const float* __restrict__ b_fine,
                                                const float* __restrict__ b_res,
                                                float* __restrict__ invbuf,
                                                float* __restrict__ gap,
                                                float* __restrict__ out) {
    int bid = blockIdx.x;
    int tid = threadIdx.x;
    if (bid < 512) {
        // ---- A: softmax denominators. 9 loads batched in a static float4[9] ----
        int idx = bid * 256 + tid;                    // 0..131071 (float4 index)
        int b   = idx >> 12;                          // 4096 float4 per image
        int pos = (idx & 4095) << 2;
        const float* base = logits + (((size_t)b * NP) << 14) + pos;
        float s0 = 0.f, s1 = 0.f, s2 = 0.f, s3 = 0.f;
        for (int g = 0; g < 9; ++g) {
            float4 v[9];
#pragma unroll
            for (int u = 0; u < 9; ++u)
                v[u] = *(const float4*)&base[(size_t)(9 * g + u) << 14];
#pragma unroll
            for (int u = 0; u < 9; ++u) {
                s0 += __expf(v[u].x); s1 += __expf(v[u].y);
                s2 += __expf(v[u].z); s3 += __expf(v[u].w);
            }
        }
        *(float4*)&invbuf[(size_t)idx << 2] =
            make_float4(1.f / s0, 1.f / s1, 1.f / s2, 1.f / s3);
    } else {
        // ---- B: gap sums + 1x1 base + biases + up(ms) -> out (4 px/thread) ----
        int gid = bid - 512;                          // 0..511
        int b = gid >> 4, strip = gid & 15;
        int row = (strip << 3) + (tid >> 5);
        int x0  = (tid & 31) << 2;
        int poff = (row << 7) + x0;
        int lane = tid & 63;
        const float* fb = feat + (((size_t)b * NFEAT) << 14);
        float a[4][4];
#pragma unroll
        for (int j = 0; j < 4; ++j)
#pragma unroll
            for (int o = 0; o < 4; ++o) a[j][o] = 0.f;
        for (int c = 0; c < NFEAT; ++c) {
            float4 f = *(const float4*)&fb[((size_t)c << 14) + poff];
            float wr0 = w_res[c], wr1 = w_res[NFEAT + c];
            float wr2 = w_res[2 * NFEAT + c], wr3 = w_res[3 * NFEAT + c];
            a[0][0] += wr0 * f.x; a[0][1] += wr1 * f.x; a[0][2] += wr2 * f.x; a[0][3] += wr3 * f.x;
            a[1][0] += wr0 * f.y; a[1][1] += wr1 * f.y; a[1][2] += wr2 * f.y; a[1][3] += wr3 * f.y;
            a[2][0] += wr0 * f.z; a[2][1] += wr1 * f.z; a[2][2] += wr2 * f.z; a[2][3] += wr3 * f.z;
            a[3][0] += wr0 * f.w; a[3][1] += wr1 * f.w; a[3][2] += wr2 * f.w; a[3][3] += wr3 * f.w;
            if (c >= C1c) {
                float s = (f.x + f.y) + (f.z + f.w);
                s += __shfl_xor(s, 1);  s += __shfl_xor(s, 2);  s += __shfl_xor(s, 4);
                s += __shfl_xor(s, 8);  s += __shfl_xor(s, 16); s += __shfl_xor(s, 32);
                if (lane == 0) atomicAdd(&gap[b * LRC + (c - C1c)], s);
            }
        }
        float syf = (row + 0.5f) * 0.25f - 0.5f;
        int y0i = (int)floorf(syf); float fy = syf - (float)y0i;
        int y0c = min(31, max(0, y0i)), y1c = min(31, max(0, y0i + 1));
        float fxv[4]; int x0v[4], x1v[4];
#pragma unroll
        for (int j = 0; j < 4; ++j) {
            float sxf = (x0 + j + 0.5f) * 0.25f - 0.5f;
            int x0i = (int)floorf(sxf);
            fxv[j] = sxf - (float)x0i;
            x0v[j] = min(31, max(0, x0i));
            x1v[j] = min(31, max(0, x0i + 1));
        }
#pragma unroll
        for (int o = 0; o < 4; ++o) {
            const float* mb = ms + ((size_t)(b * 4 + o) << 10);
            float addc = b_fine[o] + b_res[o];
            float res[4];
#pragma unroll
            for (int j = 0; j < 4; ++j) {
                float m00 = mb[(y0c << 5) + x0v[j]], m01 = mb[(y0c << 5) + x1v[j]];
                float m10 = mb[(y1c << 5) + x0v[j]], m11 = mb[(y1c << 5) + x1v[j]];
                float up = (m00 * (1.f - fxv[j]) + m01 * fxv[j]) * (1.f - fy)
                         + (m10 * (1.f - fxv[j]) + m11 * fxv[j]) * fy;
                res[j] = a[j][o] + addc + up;
            }
            *(float4*)&out[(((size_t)(b * 4 + o)) << 14) + poff] =
                make_float4(res[0], res[1], res[2], res[3]);
        }
    }
}

// ---------------- K1b: binning pass -> pm_sum[81][64] ----------------
__global__ __launch_bounds__(256) void k_sm2(const float* __restrict__ logits,
                                             const float* __restrict__ invbuf,
                                             float* __restrict__ pm_sum) {
    int bid = blockIdx.x;                 // b*81 + p
    int b = bid / NP, p = bid - b * NP;
    const float* base = logits + ((size_t)(b * NP + p) << 14);
    const float* ib   = invbuf + ((size_t)b << 14);
    int tid = threadIdx.x;
    int r0 = tid >> 5, xt = tid & 31;
    float a0 = 0.f, a1 = 0.f, a2 = 0.f, a3 = 0.f;
    int off = (r0 << 7) + (xt << 2);
#pragma unroll 4
    for (int k = 0; k < 16; ++k) {
        int o2 = off + k * 1024;
        float4 l4 = *(const float4*)&base[o2];
        float4 i4 = *(const float4*)&ib[o2];
        a0 += __expf(l4.x) * i4.x;
        a1 += __expf(l4.y) * i4.y;
        a2 += __expf(l4.z) * i4.z;
        a3 += __expf(l4.w) * i4.w;
    }
#pragma unroll
    for (int m = 2; m <= 16; m <<= 1) {
        a0 += __shfl_xor(a0, m); a1 += __shfl_xor(a1, m);
        a2 += __shfl_xor(a2, m); a3 += __shfl_xor(a3, m);
    }
    if (xt < 2) {
        int qb = p * NQ + (r0 << 3) + ((xt & 1) << 2);
        atomicAdd(&pm_sum[qb + 0], a0);
        atomicAdd(&pm_sum[qb + 1], a1);
        atomicAdd(&pm_sum[qb + 2], a2);
        atomicAdd(&pm_sum[qb + 3], a3);
    }
}

// ---------------- K3: build K (64x64), attn (32x42), rearranged weights wbuf[48][48] ----------------
__global__ __launch_bounds__(256) void k_small(const float* __restrict__ pm_sum,
                                               const float* __restrict__ gap_sum,
                                               const float* __restrict__ sigx,
                                               const float* __restrict__ sigy,
                                               const float* __restrict__ opac,
                                               const float* __restrict__ rho,
                                               const float* __restrict__ w_v2,
                                               const float* __restrict__ w_fine,
                                               const float* __restrict__ w_res,
                                               float* __restrict__ Kmat,
                                               float* __restrict__ attn,
                                               float* __restrict__ wbuf) {
    int tid = threadIdx.x;
    if (tid < 64) {
        int q = tid;
        float wsx = 0.f, wsy = 0.f, wop = 0.f, wr = 0.f;
        for (int p = 0; p < NP; ++p) {
            float pv = pm_sum[p * NQ + q] * (1.f / 8192.f);
            wsx += sigx[p] * pv;
            wsy += sigy[p] * pv;
            wop += opac[p] * pv;
            wr  += rho[p]  * pv;
        }
        float a = wsx * wsx, d = wsy * wsy, bc = wr * wsx * wsy;
        float det = a * d - bc * bc;
        float i00 = d / det, i01 = -bc / det, i11 = a / det;
        int iq = q >> 3, jq = q & 7;
        for (int h = 0; h < 8; ++h)
            for (int w = 0; w < 8; ++w) {
                int ki = h - iq + 2, kj = w - jq + 2;
                float val = 0.f;
                if (ki >= 0 && ki < 5 && kj >= 0 && kj < 5) {
                    float xx = -5.f + 2.5f * ki, yy = -5.f + 2.5f * kj;
                    val = wop * __expf(-0.5f * (i00 * xx * xx + 2.f * i01 * xx * yy + i11 * yy * yy));
                }
                Kmat[(q << 6) + (h << 3) + w] = val;
            }
    }
    for (int i = tid; i < NBATCH * LRC; i += 256) {
        int b = i / LRC, co = i % LRC;
        float s = 0.f;
        for (int ci = 0; ci < LRC; ++ci) s += w_v2[co * LRC + ci] * gap_sum[b * LRC + ci];
        s *= (1.f / 16384.f);
        attn[i] = 1.f / (1.f + __expf(-s));
    }
    for (int i = tid; i < NFEAT * 48; i += 256) {
        int c = i / 48, j = i - c * 48;
        float v = 0.f;
        if (j < 36) v = w_fine[(j / 9) * (NFEAT * 9) + c * 9 + (j % 9)];
        else if (j < 40) v = w_res[(j - 36) * NFEAT + c];
        wbuf[i] = v;
    }
}

// ---------------- K4: hr = (colors @ K) * V1 ----------------
__global__ __launch_bounds__(256) void k_hr(const float* __restrict__ feat,
                                            const float* __restrict__ V,
                                            const float* __restrict__ Kmat,
                                            float* __restrict__ hrbuf) {
    __shared__ __align__(16) float lK[4096];          // [q][pos] packed; reads broadcast
    __shared__ __align__(16) float lF[2 * 16 * 128];
    int bid = blockIdx.x;
    int b   = bid / 24;
    int r   = bid - b * 24;
    int strip = r / 3;
    int ch  = (r - strip * 3) * 2;
    int y0  = strip << 4;
    int tid = threadIdx.x;
    {
        const float4* ks = (const float4*)Kmat;
        float4* kd = (float4*)lK;
        for (int i = tid; i < 1024; i += 256) kd[i] = ks[i];
        float4* fd = (float4*)lF;
        const float* fb = feat + (((size_t)b * NFEAT + ch) << 14) + (y0 << 7);
        for (int i = tid; i < 1024; i += 256) {
            int c = i >> 9, rem = i & 511;
            fd[i] = *(const float4*)&fb[((size_t)c << 14) + (rem << 2)];
        }
    }
    __syncthreads();
    int tile = tid >> 3, hrow = tid & 7;
    int tr = tile >> 4, tx = tile & 15;
    float acc[2][8];
#pragma unroll
    for (int c = 0; c < 2; ++c)
#pragma unroll
        for (int j = 0; j < 8; ++j) acc[c][j] = 0.f;
    int fbase = (tr << 3) * 128 + (tx << 3);
    for (int q = 0; q < 64; ++q) {
        int iq = q >> 3, jq = q & 7;
        const float4 k0 = *(const float4*)&lK[(q << 6) + (hrow << 3)];
        const float4 k1 = *(const float4*)&lK[(q << 6) + (hrow << 3) + 4];
#pragma unroll
        for (int c = 0; c < 2; ++c) {
            float col = lF[(c << 11) + fbase + (iq << 7) + jq];
            acc[c][0] += col * k0.x; acc[c][1] += col * k0.y;
            acc[c][2] += col * k0.z; acc[c][3] += col * k0.w;
            acc[c][4] += col * k1.x; acc[c][5] += col * k1.y;
            acc[c][6] += col * k1.z; acc[c][7] += col * k1.w;
        }
    }
    int y = y0 + (tr << 3) + hrow;
#pragma unroll
    for (int c = 0; c < 2; ++c) {
        const float4* vp = (const float4*)(V + (((size_t)b * NFEAT + ch + c) << 14) + ((size_t)y << 7) + (tx << 3));
        float4 v0 = vp[0], v1 = vp[1];
        float4 r0, r1;
        r0.x = acc[c][0] * v0.x; r0.y = acc[c][1] * v0.y; r0.z = acc[c][2] * v0.z; r0.w = acc[c][3] * v0.w;
        r1.x = acc[c][4] * v1.x; r1.y = acc[c][5] * v1.y; r1.z = acc[c][6] * v1.z; r1.w = acc[c][7] * v1.w;
        float4* op = (float4*)(hrbuf + (((size_t)b * C1c + ch + c) << 14) + ((size_t)y << 7) + (tx << 3));
        op[0] = r0; op[1] = r1;
    }
}

// ---------------- K5: conv3x3 (RMW onto base), double-buffered LDS + reg-staged prefetch ----
#define CHN 6
__global__ __launch_bounds__(512, 4) void k_conv(const float* __restrict__ feat,
                                                 const float* __restrict__ V,
                                                 const float* __restrict__ wbuf,
                                                 const float* __restrict__ hrbuf,
                                                 const float* __restrict__ attn,
                                                 float* __restrict__ out) {
    __shared__ float s_in[2][CHN][18 * 40];   // 34.5 KB
    int bid0 = blockIdx.x;
    int rid  = (bid0 & 7) * 128 + (bid0 >> 3);    // bijective XCD swizzle (1024 = 8*128)
    int b    = rid >> 5;
    int t32  = rid & 31;
    int ty0  = (t32 >> 2) << 4;
    int tx0  = (t32 & 3) << 5;
    int tid  = threadIdx.x;               // 0..511
    int grpu = __builtin_amdgcn_readfirstlane(tid >> 8);   // 0/1, wave-uniform
    int ct   = tid & 255;
    int rp   = ct >> 5;                   // 0..7 (row pair)
    int j    = ct & 31;                   // col 0..31
    int gx   = tx0 + j;
    int gy0  = ty0 + 2 * rp;
    int cbase = (2 * rp) * 40 + 3 + j;

    // staging own pixel (1 px per thread over the 16x32 tile)
    int srow = tid >> 5, scol = tid & 31;
    int sg = ((ty0 + srow) << 7) + tx0 + scol;
    int sl = (srow + 1) * 40 + 4 + scol;

    // halo ring: 100 positions
    bool hhas = tid < 100;
    int rr, cc;
    if (tid < 34)      { rr = 0;        cc = tid; }
    else if (tid < 68) { rr = 17;       cc = tid - 34; }
    else if (tid < 84) { rr = tid - 67; cc = 0; }
    else               { rr = tid - 83; cc = 33; }
    int hsy = ty0 - 1 + rr, hsx = tx0 - 1 + cc;
    float hfm = (hsy >= 0 && hsy < HH && hsx >= 0 && hsx < WW) ? 1.f : 0.f;
    int hoff = (min(HH - 1, max(0, hsy)) << 7) + min(WW - 1, max(0, hsx));
    int hlds = rr * 40 + 3 + cc;

    const float* atb = attn + b * LRC;
    float a0[4] = {0.f, 0.f, 0.f, 0.f};
    float a1[4] = {0.f, 0.f, 0.f, 0.f};
    float rA[CHN], rB[CHN], rHA[CHN], rHB[CHN], amv[CHN];

    // ---- prologue: chunk 0 = hr channels 0..5 (pure copy) ----
#pragma unroll
    for (int k = 0; k < CHN; ++k) {
        const float* hs = hrbuf + (((size_t)(b * C1c + k)) << 14);
        rA[k]  = hs[sg];
        rHA[k] = hhas ? hs[hoff] : 0.f;
    }
#pragma unroll
    for (int k = 0; k < CHN; ++k) {
        s_in[0][k][sl] = rA[k];
        if (hhas) s_in[0][k][hlds] = rHA[k] * hfm;
    }
    int cur = 0;
    for (int t = 0; t < 8; ++t) {
        __syncthreads();
        // ---- issue next chunk's loads (channels 6(t+1)..6(t+1)+5, always feat*V) ----
        if (t < 7) {
            int c0 = CHN * (t + 1);
#pragma unroll
            for (int k = 0; k < CHN; ++k) {
                int c = c0 + k;
                const float* fs = feat + (((size_t)(b * NFEAT + c)) << 14);
                const float* vs = V    + (((size_t)(b * NFEAT + c)) << 14);
                rA[k] = fs[sg];
                rB[k] = vs[sg];
                amv[k] = atb[c - C1c];
                rHA[k] = hhas ? fs[hoff] : 0.f;
                rHB[k] = hhas ? vs[hoff] : 0.f;
            }
        }
        // ---- compute current chunk (hides the loads above) ----
        int c0c = CHN * t;
        for (int k = 0; k < 3; ++k) {
            int slot = 3 * grpu + k;
            int c = c0c + slot;
            const float* wc = wbuf + c * 48;          // uniform -> s_load
            const float* sp = &s_in[cur][slot][cbase];
            float t00 = sp[0],   t01 = sp[1],   t02 = sp[2];
            float t10 = sp[40],  t11 = sp[41],  t12 = sp[42];
            float t20 = sp[80],  t21 = sp[81],  t22 = sp[82];
            float t30 = sp[120], t31 = sp[121], t32 = sp[122];
#pragma unroll
            for (int o = 0; o < 4; ++o) {
                float w0 = wc[o * 9 + 0], w1 = wc[o * 9 + 1], w2 = wc[o * 9 + 2];
                float w3 = wc[o * 9 + 3], w4 = wc[o * 9 + 4], w5 = wc[o * 9 + 5];
                float w6 = wc[o * 9 + 6], w7 = wc[o * 9 + 7], w8 = wc[o * 9 + 8];
                a0[o] += w0 * t00 + w1 * t01 + w2 * t02
                       + w3 * t10 + w4 * t11 + w5 * t12
                       + w6 * t20 + w7 * t21 + w8 * t22;
                a1[o] += w0 * t10 + w1 * t11 + w2 * t12
                       + w3 * t20 + w4 * t21 + w5 * t22
                       + w6 * t30 + w7 * t31 + w8 * t32;
            }
        }
        // ---- write prefetched chunk to the other buffer ----
        if (t < 7) {
            int nxt = cur ^ 1;
#pragma unroll
            for (int k = 0; k < CHN; ++k) {
                s_in[nxt][k][sl] = rA[k] * rB[k] * amv[k];
                if (hhas) s_in[nxt][k][hlds] = rHA[k] * rHB[k] * (amv[k] * hfm);
            }
        }
        cur ^= 1;
    }
    // ---- merge group1 -> group0, then RMW stores (group0 only) ----
    __syncthreads();
    float* sm = &s_in[0][0][0];                  // reuse LDS (2048 floats needed)
    int p0 = (2 * rp) * 32 + j, p1 = p0 + 32;
    if (grpu == 1) {
#pragma unroll
        for (int o = 0; o < 4; ++o) { sm[o * 512 + p0] = a0[o]; sm[o * 512 + p1] = a1[o]; }
    }
    __syncthreads();
    if (grpu == 0) {
#pragma unroll
        for (int o = 0; o < 4; ++o) {
            size_t obase = ((size_t)(b * 4 + o)) << 14;
            float* op0 = out + obase + (gy0 << 7) + gx;
            float* op1 = out + obase + ((gy0 + 1) << 7) + gx;
            *op0 = *op0 + a0[o] + sm[o * 512 + p0];
            *op1 = *op1 + a1[o] + sm[o * 512 + p1];
        }
    }
}

extern "C" void kernel_launch(void* const* d_in, const int* in_sizes, int n_in,
                              void* d_out, int out_size, void* d_ws, size_t ws_size,
                              hipStream_t stream) {
    (void)in_sizes; (void)n_in; (void)out_size; (void)ws_size;
    const float* ms     = (const float*)d_in[0];
    const float* feat   = (const float*)d_in[1];
    const float* V      = (const float*)d_in[2];
    const float* logits = (const float*)d_in[3];
    const float* sigx   = (const float*)d_in[4];
    const float* sigy   = (const float*)d_in[5];
    const float* opac   = (const float*)d_in[6];
    const float* rho    = (const float*)d_in[7];
    const float* w_v2   = (const float*)d_in[8];
    const float* w_fine = (const float*)d_in[9];
    const float* b_fine = (const float*)d_in[10];
    const float* w_res  = (const float*)d_in[11];
    const float* b_res  = (const float*)d_in[12];
    float* ws  = (float*)d_ws;
    float* out = (float*)d_out;
    float* inv = ws + OFF_HR;   // disjoint lifetime with hrbuf (consumed by sm2 before k_hr)

    // zero pm_sum + gap
    hipMemsetAsync(ws + OFF_PM, 0, (size_t)(NP * NQ + NBATCH * LRC) * sizeof(float), stream);
    k_phase1<<<512 + 512, 256, 0, stream>>>(logits, feat, ms, w_res, b_fine, b_res,
                                            inv, ws + OFF_GAP, out);
    k_sm2<<<NBATCH * NP, 256, 0, stream>>>(logits, inv, ws + OFF_PM);
    k_small<<<1, 256, 0, stream>>>(ws + OFF_PM, ws + OFF_GAP, sigx, sigy, opac, rho, w_v2,
                                   w_fine, w_res, ws + OFF_K, ws + OFF_ATTN, ws + OFF_WB);
    k_hr<<<768, 256, 0, stream>>>(feat, V, ws + OFF_K, ws + OFF_HR);
    k_conv<<<1024, 512, 0, stream>>>(feat, V, ws + OFF_WB, ws + OFF_HR, ws + OFF_ATTN, out);
}

// Round 22
// 188.128 us; speedup vs baseline: 1.4679x; 1.0405x over previous
//
#include <hip/hip_runtime.h>

#define NBATCH 32
#define NFEAT 48
#define C1c 6
#define LRC 42
#define HH 128
#define WW 128
#define HWSZ 16384
#define NP 81
#define NQ 64

// workspace layout (in floats)
#define OFF_PM   0                      // 81*64 = 5184
#define OFF_GAP  5184                   // 32*42 = 1344  (contiguous after PM -> one memset)
#define OFF_K    6528                   // 64*64 = 4096
#define OFF_ATTN 10624                  // 1344
#define OFF_WB   11968                  // 48*48 = 2304 rearranged weights
#define OFF_HR   14272                  // 32*6*16384 = 3145728

// ---------------- Phase 1 (heterogeneous):
//   A (bid<512): FUSED softmax + pm binning (r6's proven structure — one cold logits pass)
//   B (bid>=512): gap sums + 1x1 base + biases + up(ms) -> out ----------------
__global__ __launch_bounds__(256, 2) void k_phase1(const float* __restrict__ logits,
                                                   const float* __restrict__ feat,
                                                   const float* __restrict__ ms,
                                                   const float* __restrict__ w_res,
                                                   const float* __restrict__ b_fine,
                                                   const float* __restrict__ b_res,
                                                   float* __restrict__ pm_sum,
                                                   float* __restrict__ gap,
                                                   float* __restrict__ out) {
    int bid = blockIdx.x;
    int tid = threadIdx.x;
    if (bid < 512) {
        // ---- A: per-pixel softmax over 81 ch, binned into pm_sum[81][64] ----
        int b   = bid >> 4;
        int ygp = (bid >> 2) & 3;
        int qq  = bid & 3;
        int x   = tid & 127;
        int yg  = ygp * 2 + (tid >> 7);
        float acc[NP];
#pragma unroll
        for (int p = 0; p < NP; ++p) acc[p] = 0.f;
        for (int k = 0; k < 4; ++k) {
            int y = yg + 8 * (qq * 4 + k);
            const float* base = logits + (size_t)b * NP * HWSZ + (y << 7) + x;
            float ev[NP];
            float s = 0.f;
#pragma unroll
            for (int p = 0; p < NP; ++p) { ev[p] = __expf(base[(size_t)p * HWSZ]); s += ev[p]; }
            float inv = 1.f / s;
#pragma unroll
            for (int p = 0; p < NP; ++p) acc[p] += ev[p] * inv;
        }
        int lane = tid & 63;
#pragma unroll
        for (int p = 0; p < NP; ++p) {
            float e = acc[p];
            e += __shfl_xor(e, 8);
            e += __shfl_xor(e, 16);
            e += __shfl_xor(e, 32);
            if (lane < 8) atomicAdd(&pm_sum[p * NQ + (yg << 3) + lane], e);
        }
    } else {
        // ---- B: gap sums + 1x1 base + biases + up(ms) -> out (4 px/thread) ----
        int gid = bid - 512;                          // 0..511
        int b = gid >> 4, strip = gid & 15;
        int row = (strip << 3) + (tid >> 5);
        int x0  = (tid & 31) << 2;
        int poff = (row << 7) + x0;
        int lane = tid & 63;
        const float* fb = feat + (((size_t)b * NFEAT) << 14);
        float a[4][4];
#pragma unroll
        for (int j = 0; j < 4; ++j)
#pragma unroll
            for (int o = 0; o < 4; ++o) a[j][o] = 0.f;
        for (int c = 0; c < NFEAT; ++c) {
            float4 f = *(const float4*)&fb[((size_t)c << 14) + poff];
            float wr0 = w_res[c], wr1 = w_res[NFEAT + c];
            float wr2 = w_res[2 * NFEAT + c], wr3 = w_res[3 * NFEAT + c];
            a[0][0] += wr0 * f.x; a[0][1] += wr1 * f.x; a[0][2] += wr2 * f.x; a[0][3] += wr3 * f.x;
            a[1][0] += wr0 * f.y; a[1][1] += wr1 * f.y; a[1][2] += wr2 * f.y; a[1][3] += wr3 * f.y;
            a[2][0] += wr0 * f.z; a[2][1] += wr1 * f.z; a[2][2] += wr2 * f.z; a[2][3] += wr3 * f.z;
            a[3][0] += wr0 * f.w; a[3][1] += wr1 * f.w; a[3][2] += wr2 * f.w; a[3][3] += wr3 * f.w;
            if (c >= C1c) {
                float s = (f.x + f.y) + (f.z + f.w);
                s += __shfl_xor(s, 1);  s += __shfl_xor(s, 2);  s += __shfl_xor(s, 4);
                s += __shfl_xor(s, 8);  s += __shfl_xor(s, 16); s += __shfl_xor(s, 32);
                if (lane == 0) atomicAdd(&gap[b * LRC + (c - C1c)], s);
            }
        }
        float syf = (row + 0.5f) * 0.25f - 0.5f;
        int y0i = (int)floorf(syf); float fy = syf - (float)y0i;
        int y0c = min(31, max(0, y0i)), y1c = min(31, max(0, y0i + 1));
        float fxv[4]; int x0v[4], x1v[4];
#pragma unroll
        for (int j = 0; j < 4; ++j) {
            float sxf = (x0 + j + 0.5f) * 0.25f - 0.5f;
            int x0i = (int)floorf(sxf);
            fxv[j] = sxf - (float)x0i;
            x0v[j] = min(31, max(0, x0i));
            x1v[j] = min(31, max(0, x0i + 1));
        }
#pragma unroll
        for (int o = 0; o < 4; ++o) {
            const float* mb = ms + ((size_t)(b * 4 + o) << 10);
            float addc = b_fine[o] + b_res[o];
            float res[4];
#pragma unroll
            for (int j = 0; j < 4; ++j) {
                float m00 = mb[(y0c << 5) + x0v[j]], m01 = mb[(y0c << 5) + x1v[j]];
                float m10 = mb[(y1c << 5) + x0v[j]], m11 = mb[(y1c << 5) + x1v[j]];
                float up = (m00 * (1.f - fxv[j]) + m01 * fxv[j]) * (1.f - fy)
                         + (m10 * (1.f - fxv[j]) + m11 * fxv[j]) * fy;
                res[j] = a[j][o] + addc + up;
            }
            *(float4*)&out[(((size_t)(b * 4 + o)) << 14) + poff] =
                make_float4(res[0], res[1], res[2], res[3]);
        }
    }
}

// ---------------- K3: build K (64x64), attn (32x42), rearranged weights wbuf[48][48] ----------------
__global__ __launch_bounds__(256) void k_small(const float* __restrict__ pm_sum,
                                               const float* __restrict__ gap_sum,
                                               const float* __restrict__ sigx,
                                               const float* __restrict__ sigy,
                                               const float* __restrict__ opac,
                                               const float* __restrict__ rho,
                                               const float* __restrict__ w_v2,
                                               const float* __restrict__ w_fine,
                                               const float* __restrict__ w_res,
                                               float* __restrict__ Kmat,
                                               float* __restrict__ attn,
                                               float* __restrict__ wbuf) {
    int tid = threadIdx.x;
    if (tid < 64) {
        int q = tid;
        float wsx = 0.f, wsy = 0.f, wop = 0.f, wr = 0.f;
        for (int p = 0; p < NP; ++p) {
            float pv = pm_sum[p * NQ + q] * (1.f / 8192.f);
            wsx += sigx[p] * pv;
            wsy += sigy[p] * pv;
            wop += opac[p] * pv;
            wr  += rho[p]  * pv;
        }
        float a = wsx * wsx, d = wsy * wsy, bc = wr * wsx * wsy;
        float det = a * d - bc * bc;
        float i00 = d / det, i01 = -bc / det, i11 = a / det;
        int iq = q >> 3, jq = q & 7;
        for (int h = 0; h < 8; ++h)
            for (int w = 0; w < 8; ++w) {
                int ki = h - iq + 2, kj = w - jq + 2;
                float val = 0.f;
                if (ki >= 0 && ki < 5 && kj >= 0 && kj < 5) {
                    float xx = -5.f + 2.5f * ki, yy = -5.f + 2.5f * kj;
                    val = wop * __expf(-0.5f * (i00 * xx * xx + 2.f * i01 * xx * yy + i11 * yy * yy));
                }
                Kmat[(q << 6) + (h << 3) + w] = val;
            }
    }
    for (int i = tid; i < NBATCH * LRC; i += 256) {
        int b = i / LRC, co = i % LRC;
        float s = 0.f;
        for (int ci = 0; ci < LRC; ++ci) s += w_v2[co * LRC + ci] * gap_sum[b * LRC + ci];
        s *= (1.f / 16384.f);
        attn[i] = 1.f / (1.f + __expf(-s));
    }
    for (int i = tid; i < NFEAT * 48; i += 256) {
        int c = i / 48, j = i - c * 48;
        float v = 0.f;
        if (j < 36) v = w_fine[(j / 9) * (NFEAT * 9) + c * 9 + (j % 9)];
        else if (j < 40) v = w_res[(j - 36) * NFEAT + c];
        wbuf[i] = v;
    }
}

// ---------------- K4: hr = (colors @ K) * V1 ----------------
__global__ __launch_bounds__(256) void k_hr(const float* __restrict__ feat,
                                            const float* __restrict__ V,
                                            const float* __restrict__ Kmat,
                                            float* __restrict__ hrbuf) {
    __shared__ __align__(16) float lK[4096];          // [q][pos] packed; reads broadcast
    __shared__ __align__(16) float lF[2 * 16 * 128];
    int bid = blockIdx.x;
    int b   = bid / 24;
    int r   = bid - b * 24;
    int strip = r / 3;
    int ch  = (r - strip * 3) * 2;
    int y0  = strip << 4;
    int tid = threadIdx.x;
    {
        const float4* ks = (const float4*)Kmat;
        float4* kd = (float4*)lK;
        for (int i = tid; i < 1024; i += 256) kd[i] = ks[i];
        float4* fd = (float4*)lF;
        const float* fb = feat + (((size_t)b * NFEAT + ch) << 14) + (y0 << 7);
        for (int i = tid; i < 1024; i += 256) {
            int c = i >> 9, rem = i & 511;
            fd[i] = *(const float4*)&fb[((size_t)c << 14) + (rem << 2)];
        }
    }
    __syncthreads();
    int tile = tid >> 3, hrow = tid & 7;
    int tr = tile >> 4, tx = tile & 15;
    float acc[2][8];
#pragma unroll
    for (int c = 0; c < 2; ++c)
#pragma unroll
        for (int j = 0; j < 8; ++j) acc[c][j] = 0.f;
    int fbase = (tr << 3) * 128 + (tx << 3);
    for (int q = 0; q < 64; ++q) {
        int iq = q >> 3, jq = q & 7;
        const float4 k0 = *(const float4*)&lK[(q << 6) + (hrow << 3)];
        const float4 k1 = *(const float4*)&lK[(q << 6) + (hrow << 3) + 4];
#pragma unroll
        for (int c = 0; c < 2; ++c) {
            float col = lF[(c << 11) + fbase + (iq << 7) + jq];
            acc[c][0] += col * k0.x; acc[c][1] += col * k0.y;
            acc[c][2] += col * k0.z; acc[c][3] += col * k0.w;
            acc[c][4] += col * k1.x; acc[c][5] += col * k1.y;
            acc[c][6] += col * k1.z; acc[c][7] += col * k1.w;
        }
    }
    int y = y0 + (tr << 3) + hrow;
#pragma unroll
    for (int c = 0; c < 2; ++c) {
        const float4* vp = (const float4*)(V + (((size_t)b * NFEAT + ch + c) << 14) + ((size_t)y << 7) + (tx << 3));
        float4 v0 = vp[0], v1 = vp[1];
        float4 r0, r1;
        r0.x = acc[c][0] * v0.x; r0.y = acc[c][1] * v0.y; r0.z = acc[c][2] * v0.z; r0.w = acc[c][3] * v0.w;
        r1.x = acc[c][4] * v1.x; r1.y = acc[c][5] * v1.y; r1.z = acc[c][6] * v1.z; r1.w = acc[c][7] * v1.w;
        float4* op = (float4*)(hrbuf + (((size_t)b * C1c + ch + c) << 14) + ((size_t)y << 7) + (tx << 3));
        op[0] = r0; op[1] = r1;
    }
}

// ---------------- K5: conv3x3 (RMW onto base), double-buffered LDS + reg-staged prefetch ----
#define CHN 6
__global__ __launch_bounds__(512, 4) void k_conv(const float* __restrict__ feat,
                                                 const float* __restrict__ V,
                                                 const float* __restrict__ wbuf,
                                                 const float* __restrict__ hrbuf,
                                                 const float* __restrict__ attn,
                                                 float* __restrict__ out) {
    __shared__ float s_in[2][CHN][18 * 40];   // 34.5 KB
    int bid0 = blockIdx.x;
    int rid  = (bid0 & 7) * 128 + (bid0 >> 3);    // bijective XCD swizzle (1024 = 8*128)
    int b    = rid >> 5;
    int t32  = rid & 31;
    int ty0  = (t32 >> 2) << 4;
    int tx0  = (t32 & 3) << 5;
    int tid  = threadIdx.x;               // 0..511
    int grpu = __builtin_amdgcn_readfirstlane(tid >> 8);   // 0/1, wave-uniform
    int ct   = tid & 255;
    int rp   = ct >> 5;                   // 0..7 (row pair)
    int j    = ct & 31;                   // col 0..31
    int gx   = tx0 + j;
    int gy0  = ty0 + 2 * rp;
    int cbase = (2 * rp) * 40 + 3 + j;

    // staging own pixel (1 px per thread over the 16x32 tile)
    int srow = tid >> 5, scol = tid & 31;
    int sg = ((ty0 + srow) << 7) + tx0 + scol;
    int sl = (srow + 1) * 40 + 4 + scol;

    // halo ring: 100 positions
    bool hhas = tid < 100;
    int rr, cc;
    if (tid < 34)      { rr = 0;        cc = tid; }
    else if (tid < 68) { rr = 17;       cc = tid - 34; }
    else if (tid < 84) { rr = tid - 67; cc = 0; }
    else               { rr = tid - 83; cc = 33; }
    int hsy = ty0 - 1 + rr, hsx = tx0 - 1 + cc;
    float hfm = (hsy >= 0 && hsy < HH && hsx >= 0 && hsx < WW) ? 1.f : 0.f;
    int hoff = (min(HH - 1, max(0, hsy)) << 7) + min(WW - 1, max(0, hsx));
    int hlds = rr * 40 + 3 + cc;

    const float* atb = attn + b * LRC;
    float a0[4] = {0.f, 0.f, 0.f, 0.f};
    float a1[4] = {0.f, 0.f, 0.f, 0.f};
    float rA[CHN], rB[CHN], rHA[CHN], rHB[CHN], amv[CHN];

    // ---- prologue: chunk 0 = hr channels 0..5 (pure copy) ----
#pragma unroll
    for (int k = 0; k < CHN; ++k) {
        const float* hs = hrbuf + (((size_t)(b * C1c + k)) << 14);
        rA[k]  = hs[sg];
        rHA[k] = hhas ? hs[hoff] : 0.f;
    }
#pragma unroll
    for (int k = 0; k < CHN; ++k) {
        s_in[0][k][sl] = rA[k];
        if (hhas) s_in[0][k][hlds] = rHA[k] * hfm;
    }
    int cur = 0;
    for (int t = 0; t < 8; ++t) {
        __syncthreads();
        // ---- issue next chunk's loads (channels 6(t+1)..6(t+1)+5, always feat*V) ----
        if (t < 7) {
            int c0 = CHN * (t + 1);
#pragma unroll
            for (int k = 0; k < CHN; ++k) {
                int c = c0 + k;
                const float* fs = feat + (((size_t)(b * NFEAT + c)) << 14);
                const float* vs = V    + (((size_t)(b * NFEAT + c)) << 14);
                rA[k] = fs[sg];
                rB[k] = vs[sg];
                amv[k] = atb[c - C1c];
                rHA[k] = hhas ? fs[hoff] : 0.f;
                rHB[k] = hhas ? vs[hoff] : 0.f;
            }
        }
        // ---- compute current chunk (hides the loads above) ----
        int c0c = CHN * t;
        for (int k = 0; k < 3; ++k) {
            int slot = 3 * grpu + k;
            int c = c0c + slot;
            const float* wc = wbuf + c * 48;          // uniform -> s_load
            const float* sp = &s_in[cur][slot][cbase];
            float t00 = sp[0],   t01 = sp[1],   t02 = sp[2];
            float t10 = sp[40],  t11 = sp[41],  t12 = sp[42];
            float t20 = sp[80],  t21 = sp[81],  t22 = sp[82];
            float t30 = sp[120], t31 = sp[121], t32 = sp[122];
#pragma unroll
            for (int o = 0; o < 4; ++o) {
                float w0 = wc[o * 9 + 0], w1 = wc[o * 9 + 1], w2 = wc[o * 9 + 2];
                float w3 = wc[o * 9 + 3], w4 = wc[o * 9 + 4], w5 = wc[o * 9 + 5];
                float w6 = wc[o * 9 + 6], w7 = wc[o * 9 + 7], w8 = wc[o * 9 + 8];
                a0[o] += w0 * t00 + w1 * t01 + w2 * t02
                       + w3 * t10 + w4 * t11 + w5 * t12
                       + w6 * t20 + w7 * t21 + w8 * t22;
                a1[o] += w0 * t10 + w1 * t11 + w2 * t12
                       + w3 * t20 + w4 * t21 + w5 * t22
                       + w6 * t30 + w7 * t31 + w8 * t32;
            }
        }
        // ---- write prefetched chunk to the other buffer ----
        if (t < 7) {
            int nxt = cur ^ 1;
#pragma unroll
            for (int k = 0; k < CHN; ++k) {
                s_in[nxt][k][sl] = rA[k] * rB[k] * amv[k];
                if (hhas) s_in[nxt][k][hlds] = rHA[k] * rHB[k] * (amv[k] * hfm);
            }
        }
        cur ^= 1;
    }
    // ---- merge group1 -> group0, then RMW stores (group0 only) ----
    __syncthreads();
    float* sm = &s_in[0][0][0];                  // reuse LDS (2048 floats needed)
    int p0 = (2 * rp) * 32 + j, p1 = p0 + 32;
    if (grpu == 1) {
#pragma unroll
        for (int o = 0; o < 4; ++o) { sm[o * 512 + p0] = a0[o]; sm[o * 512 + p1] = a1[o]; }
    }
    __syncthreads();
    if (grpu == 0) {
#pragma unroll
        for (int o = 0; o < 4; ++o) {
            size_t obase = ((size_t)(b * 4 + o)) << 14;
            float* op0 = out + obase + (gy0 << 7) + gx;
            float* op1 = out + obase + ((gy0 + 1) << 7) + gx;
            *op0 = *op0 + a0[o] + sm[o * 512 + p0];
            *op1 = *op1 + a1[o] + sm[o * 512 + p1];
        }
    }
}

extern "C" void kernel_launch(void* const* d_in, const int* in_sizes, int n_in,
                              void* d_out, int out_size, void* d_ws, size_t ws_size,
                              hipStream_t stream) {
    (void)in_sizes; (void)n_in; (void)out_size; (void)ws_size;
    const float* ms     = (const float*)d_in[0];
    const float* feat   = (const float*)d_in[1];
    const float* V      = (const float*)d_in[2];
    const float* logits = (const float*)d_in[3];
    const float* sigx   = (const float*)d_in[4];
    const float* sigy   = (const float*)d_in[5];
    const float* opac   = (const float*)d_in[6];
    const float* rho    = (const float*)d_in[7];
    const float* w_v2   = (const float*)d_in[8];
    const float* w_fine = (const float*)d_in[9];
    const float* b_fine = (const float*)d_in[10];
    const float* w_res  = (const float*)d_in[11];
    const float* b_res  = (const float*)d_in[12];
    float* ws  = (float*)d_ws;
    float* out = (float*)d_out;

    // zero pm_sum + gap (contiguous -> one memset)
    hipMemsetAsync(ws + OFF_PM, 0, (size_t)(NP * NQ + NBATCH * LRC) * sizeof(float), stream);
    k_phase1<<<512 + 512, 256, 0, stream>>>(logits, feat, ms, w_res, b_fine, b_res,
                                            ws + OFF_PM, ws + OFF_GAP, out);
    k_small<<<1, 256, 0, stream>>>(ws + OFF_PM, ws + OFF_GAP, sigx, sigy, opac, rho, w_v2,
                                   w_fine, w_res, ws + OFF_K, ws + OFF_ATTN, ws + OFF_WB);
    k_hr<<<768, 256, 0, stream>>>(feat, V, ws + OFF_K, ws + OFF_HR);
    k_conv<<<1024, 512, 0, stream>>>(feat, V, ws + OFF_WB, ws + OFF_HR, ws + OFF_ATTN, out);
}